// Round 3
// baseline (991.192 us; speedup 1.0000x reference)
//
#include <hip/hip_runtime.h>

typedef unsigned short u16;
typedef unsigned int   u32;

// ---- bf16 helpers (pack fp32 -> bf16 RNE; unpack = <<16) ----
__device__ __forceinline__ float bf2f(u16 v) {
    union { u32 i; float f; } x; x.i = ((u32)v) << 16; return x.f;
}
__device__ __forceinline__ u16 f2bf(float f) {
    union { u32 i; float f; } x; x.f = f;
    u32 r = x.i + 0x7fffu + ((x.i >> 16) & 1u);
    return (u16)(r >> 16);
}

// ======================= Projection GEMM =======================
// C[m][n] = sum_k X[m][k] * W[n][k]   (torch Linear: y = x @ W^T)
// X: [8192, 512] fp32 row-major, W: [512, 512] fp32 row-major.
// Output: bf16 workspace (threshold is 2% relative -> bf16 intermediates OK).
// 64x64 tile per block, BK=32, 256 threads, 4x4 acc per thread.
#define PD 512

__global__ __launch_bounds__(256) void proj_gemm(
    const float* __restrict__ query, const float* __restrict__ keys,
    const float* __restrict__ Wq, const float* __restrict__ Wk, const float* __restrict__ Wv,
    u16* __restrict__ Qo, u16* __restrict__ Ko, u16* __restrict__ Vo)
{
    const int z = blockIdx.z;
    const float* __restrict__ X = (z == 0) ? query : keys;
    const float* __restrict__ W = (z == 0) ? Wq : ((z == 1) ? Wk : Wv);
    u16* __restrict__ O         = (z == 0) ? Qo : ((z == 1) ? Ko : Vo);

    __shared__ float Xs[32][68];   // [k][m], pad 68 keeps float4 rows 16B-aligned
    __shared__ float Ws[32][68];   // [k][n]

    const int tid = threadIdx.x;
    const int tm  = tid >> 4;        // 0..15 -> rows tm*4..+3
    const int tn  = tid & 15;        // 0..15 -> cols tn*4..+3
    const int gm  = blockIdx.x * 64;
    const int gn  = blockIdx.y * 64;
    const int lr  = tid >> 2;        // 0..63 load row
    const int lc  = (tid & 3) << 3;  // 0,8,16,24 -> 8 fp32 per thread (64x32 tile)

    float acc[4][4] = {};

    for (int k0 = 0; k0 < PD; k0 += 32) {
        __syncthreads();
        float4 xv0 = *(const float4*)(X + (size_t)(gm + lr) * PD + k0 + lc);
        float4 xv1 = *(const float4*)(X + (size_t)(gm + lr) * PD + k0 + lc + 4);
        float4 wv0 = *(const float4*)(W + (size_t)(gn + lr) * PD + k0 + lc);
        float4 wv1 = *(const float4*)(W + (size_t)(gn + lr) * PD + k0 + lc + 4);
        const float* xs = (const float*)&xv0;   // xv0,xv1 contiguous? not guaranteed; handle separately
        Xs[lc + 0][lr] = xv0.x; Xs[lc + 1][lr] = xv0.y;
        Xs[lc + 2][lr] = xv0.z; Xs[lc + 3][lr] = xv0.w;
        Xs[lc + 4][lr] = xv1.x; Xs[lc + 5][lr] = xv1.y;
        Xs[lc + 6][lr] = xv1.z; Xs[lc + 7][lr] = xv1.w;
        Ws[lc + 0][lr] = wv0.x; Ws[lc + 1][lr] = wv0.y;
        Ws[lc + 2][lr] = wv0.z; Ws[lc + 3][lr] = wv0.w;
        Ws[lc + 4][lr] = wv1.x; Ws[lc + 5][lr] = wv1.y;
        Ws[lc + 6][lr] = wv1.z; Ws[lc + 7][lr] = wv1.w;
        (void)xs;
        __syncthreads();
        #pragma unroll
        for (int kk = 0; kk < 32; ++kk) {
            float4 xa = *(const float4*)&Xs[kk][tm << 2];
            float4 wb = *(const float4*)&Ws[kk][tn << 2];
            float a[4] = {xa.x, xa.y, xa.z, xa.w};
            float c[4] = {wb.x, wb.y, wb.z, wb.w};
            #pragma unroll
            for (int i = 0; i < 4; ++i)
                #pragma unroll
                for (int j = 0; j < 4; ++j)
                    acc[i][j] = fmaf(a[i], c[j], acc[i][j]);
        }
    }

    #pragma unroll
    for (int i = 0; i < 4; ++i) {
        const int row = gm + (tm << 2) + i;
        ushort4 ov;
        ov.x = f2bf(acc[i][0]); ov.y = f2bf(acc[i][1]);
        ov.z = f2bf(acc[i][2]); ov.w = f2bf(acc[i][3]);
        *(ushort4*)(O + (size_t)row * PD + gn + (tn << 2)) = ov;
    }
}

// ======================= Flash attention =======================
// One block per (b, h, q-tile of 64). 256 threads; thread (tm,tn) owns
// rows tm*4..+3 and (cols of S | head-dims of O) tn*4..+3.
// Q/K/V read from bf16 workspace; residual read from fp32 query; fp32 out.
__global__ __launch_bounds__(256) void attn_kernel(
    const u16* __restrict__ Qp, const u16* __restrict__ Kp, const u16* __restrict__ Vp,
    const float* __restrict__ query, float* __restrict__ out)
{
    const int qt = blockIdx.x;   // 0..31
    const int h  = blockIdx.y;   // 0..7
    const int b  = blockIdx.z;   // 0..3
    const int q0 = qt << 6;
    const int L = 2048, D = 512;
    const float inv_scale = 0.044194173824159216f;  // 1/sqrt(512)  (sqrt(D), not sqrt(dh))

    __shared__ float Qs[64][64];   // [d][m], pre-scaled
    __shared__ float Ks[64][64];   // [d][n]
    __shared__ float Vs[64][64];   // [k][c]
    __shared__ float Ps[64][64];   // [k][m], XOR-swizzled rows

    const int tid = threadIdx.x;
    const int tm  = tid >> 4;
    const int tn  = tid & 15;
    const int lr  = tid >> 2;        // 0..63 load row
    const int lc  = (tid & 3) << 4;  // 0,16,32,48 -> 16 bf16 per thread (full 64 head dims)

    // Load Q tile (scaled by 1/sqrt(512) here, in fp32)
    {
        const size_t base = ((size_t)(b * L + q0 + lr)) * D + h * 64 + lc;
        #pragma unroll
        for (int half = 0; half < 2; ++half) {
            uint4 qv = *(const uint4*)(Qp + base + half * 8);
            const u32* qw = (const u32*)&qv;
            #pragma unroll
            for (int w = 0; w < 4; ++w) {
                const int d = lc + half * 8 + 2 * w;
                union { u32 i; float f; } a, c;
                a.i = qw[w] << 16;          Qs[d][lr]     = a.f * inv_scale;
                c.i = qw[w] & 0xffff0000u;  Qs[d + 1][lr] = c.f * inv_scale;
            }
        }
    }

    float o[4][4] = {};
    float m_i[4], l_i[4];
    #pragma unroll
    for (int i = 0; i < 4; ++i) { m_i[i] = -INFINITY; l_i[i] = 0.f; }

    for (int k0 = 0; k0 < L; k0 += 64) {
        __syncthreads();   // prior iteration done reading Ks/Vs/Ps
        {
            const size_t kb = ((size_t)(b * L + k0 + lr)) * D + h * 64 + lc;
            #pragma unroll
            for (int half = 0; half < 2; ++half) {
                uint4 kv = *(const uint4*)(Kp + kb + half * 8);
                uint4 vv = *(const uint4*)(Vp + kb + half * 8);
                const u32* kw = (const u32*)&kv;
                const u32* vw = (const u32*)&vv;
                #pragma unroll
                for (int w = 0; w < 4; ++w) {
                    const int d = lc + half * 8 + 2 * w;
                    union { u32 i; float f; } a, c;
                    a.i = kw[w] << 16;          Ks[d][lr]     = a.f;
                    c.i = kw[w] & 0xffff0000u;  Ks[d + 1][lr] = c.f;
                    a.i = vw[w] << 16;          Vs[lr][d]     = a.f;
                    c.i = vw[w] & 0xffff0000u;  Vs[lr][d + 1] = c.f;
                }
            }
        }
        __syncthreads();

        // S tile: s[i][j] = sum_d Q[d][row] * K[d][key]
        float s[4][4] = {};
        #pragma unroll
        for (int kk = 0; kk < 64; ++kk) {
            float4 qa = *(const float4*)&Qs[kk][tm << 2];
            float4 kb = *(const float4*)&Ks[kk][tn << 2];
            float a[4] = {qa.x, qa.y, qa.z, qa.w};
            float c[4] = {kb.x, kb.y, kb.z, kb.w};
            #pragma unroll
            for (int i = 0; i < 4; ++i)
                #pragma unroll
                for (int j = 0; j < 4; ++j)
                    s[i][j] = fmaf(a[i], c[j], s[i][j]);
        }

        // online softmax update (per row i)
        #pragma unroll
        for (int i = 0; i < 4; ++i) {
            float rm = fmaxf(fmaxf(s[i][0], s[i][1]), fmaxf(s[i][2], s[i][3]));
            rm = fmaxf(rm, __shfl_xor(rm, 1));
            rm = fmaxf(rm, __shfl_xor(rm, 2));
            rm = fmaxf(rm, __shfl_xor(rm, 4));
            rm = fmaxf(rm, __shfl_xor(rm, 8));
            float m_new = fmaxf(m_i[i], rm);
            float alpha = __expf(m_i[i] - m_new);   // exp(-inf)=0 on first tile
            float rs = 0.f;
            #pragma unroll
            for (int j = 0; j < 4; ++j) {
                s[i][j] = __expf(s[i][j] - m_new);
                rs += s[i][j];
            }
            rs += __shfl_xor(rs, 1);
            rs += __shfl_xor(rs, 2);
            rs += __shfl_xor(rs, 4);
            rs += __shfl_xor(rs, 8);
            l_i[i] = l_i[i] * alpha + rs;
            m_i[i] = m_new;
            #pragma unroll
            for (int j = 0; j < 4; ++j) o[i][j] *= alpha;
        }

        // P -> LDS (k-major, XOR swizzle on row index to break bank conflicts)
        #pragma unroll
        for (int i = 0; i < 4; ++i) {
            const int r = (tm << 2) + i;
            #pragma unroll
            for (int j = 0; j < 4; ++j) {
                const int c = (tn << 2) + j;
                Ps[c][r ^ ((c & 15) << 2)] = s[i][j];
            }
        }
        __syncthreads();

        // O += P @ V
        #pragma unroll
        for (int kk = 0; kk < 64; ++kk) {
            float4 pa = *(const float4*)&Ps[kk][(tm << 2) ^ ((kk & 15) << 2)];
            float4 vb = *(const float4*)&Vs[kk][tn << 2];
            float a[4] = {pa.x, pa.y, pa.z, pa.w};
            float c[4] = {vb.x, vb.y, vb.z, vb.w};
            #pragma unroll
            for (int i = 0; i < 4; ++i)
                #pragma unroll
                for (int j = 0; j < 4; ++j)
                    o[i][j] = fmaf(a[i], c[j], o[i][j]);
        }
    }

    // epilogue: normalize, add residual (fp32 query), store fp32
    #pragma unroll
    for (int i = 0; i < 4; ++i) {
        const int r = q0 + (tm << 2) + i;
        const float inv_l = 1.0f / l_i[i];
        const size_t base = ((size_t)(b * L + r)) * D + h * 64 + (tn << 2);
        float4 qres = *(const float4*)(query + base);
        float4 ov;
        ov.x = fmaf(o[i][0], inv_l, qres.x);
        ov.y = fmaf(o[i][1], inv_l, qres.y);
        ov.z = fmaf(o[i][2], inv_l, qres.z);
        ov.w = fmaf(o[i][3], inv_l, qres.w);
        *(float4*)(out + base) = ov;
    }
}

// ======================= launch =======================
extern "C" void kernel_launch(void* const* d_in, const int* in_sizes, int n_in,
                              void* d_out, int out_size, void* d_ws, size_t ws_size,
                              hipStream_t stream) {
    const float* query = (const float*)d_in[0];   // [4,2048,512] fp32
    const float* keys  = (const float*)d_in[1];   // [4,2048,512] fp32
    const float* Wq    = (const float*)d_in[2];   // [512,512] fp32
    const float* Wk    = (const float*)d_in[3];
    const float* Wv    = (const float*)d_in[4];
    float* out = (float*)d_out;

    // workspace: Q, K, V projections as bf16, [8192, 512] each = 24 MB total
    u16* Qp = (u16*)d_ws;
    u16* Kp = Qp + (size_t)8192 * 512;
    u16* Vp = Kp + (size_t)8192 * 512;

    proj_gemm<<<dim3(128, 8, 3), 256, 0, stream>>>(query, keys, Wq, Wk, Wv, Qp, Kp, Vp);
    attn_kernel<<<dim3(32, 8, 4), 256, 0, stream>>>(Qp, Kp, Vp, query, out);
}

// Round 4
// 188.946 us; speedup vs baseline: 5.2459x; 5.2459x over previous
//
#include <hip/hip_runtime.h>

typedef unsigned short u16;
typedef unsigned int   u32;
typedef short  s16x8  __attribute__((ext_vector_type(8)));
typedef float  f32x16 __attribute__((ext_vector_type(16)));

__device__ __forceinline__ u16 f2bf(float f) {
    union { u32 i; float f; } x; x.f = f;
    u32 r = x.i + 0x7fffu + ((x.i >> 16) & 1u);
    return (u16)(r >> 16);
}

#define PD 512

// ======================= Projection GEMM (MFMA) =======================
// z=0: Q = query @ Wq^T  -> Qo[8192][512] bf16 (scaled by 1/sqrt(512))
// z=1: K = keys  @ Wk^T  -> Ko[8192][512] bf16
// z=2: V^T = Wv @ keys^T -> Vt[(b*8+h)*64+dh][2048] bf16 (transposed store)
// All three are "A rows x B rows, contract contiguous k" MFMA GEMMs.
__global__ __launch_bounds__(256) void proj_mfma(
    const float* __restrict__ query, const float* __restrict__ keys,
    const float* __restrict__ Wq, const float* __restrict__ Wk, const float* __restrict__ Wv,
    u16* __restrict__ Qo, u16* __restrict__ Ko, u16* __restrict__ Vt)
{
    const int z = blockIdx.z;
    const float* __restrict__ X = (z == 0) ? query : keys;
    const float* __restrict__ W = (z == 0) ? Wq : ((z == 1) ? Wk : Wv);
    const int bx = blockIdx.x;   // 0..63 token-tile (128)
    const int by = blockIdx.y;   // 0..3  outdim-tile (128)

    const float* __restrict__ Amat = (z < 2) ? X : W;
    const float* __restrict__ Bmat = (z < 2) ? W : X;
    const int a0 = ((z < 2) ? bx : by) * 128;
    const int b0 = ((z < 2) ? by : bx) * 128;

    __shared__ u16 As[128][40];   // [row][k], +8 pad: 16B-aligned rows, conflicts <=4-way
    __shared__ u16 Bs[128][40];

    const int tid  = threadIdx.x;
    const int wave = tid >> 6, lane = tid & 63;
    const int wm = wave >> 1, wn = wave & 1;
    const int l31 = lane & 31, lh = lane >> 5;

    const int srow = tid >> 1;         // 0..127 staging row
    const int sk   = (tid & 1) * 16;   // 0/16   staging k-offset

    f32x16 acc[2][2];
    #pragma unroll
    for (int i = 0; i < 2; ++i)
        #pragma unroll
        for (int j = 0; j < 2; ++j)
            #pragma unroll
            for (int r = 0; r < 16; ++r) acc[i][j][r] = 0.f;

    for (int k0 = 0; k0 < PD; k0 += 32) {
        __syncthreads();
        {
            const float* ap = Amat + (size_t)(a0 + srow) * PD + k0 + sk;
            const float* bp = Bmat + (size_t)(b0 + srow) * PD + k0 + sk;
            u16 ab[16], bb[16];
            #pragma unroll
            for (int i = 0; i < 16; i += 4) {
                float4 av = *(const float4*)(ap + i);
                float4 bv = *(const float4*)(bp + i);
                ab[i+0] = f2bf(av.x); ab[i+1] = f2bf(av.y); ab[i+2] = f2bf(av.z); ab[i+3] = f2bf(av.w);
                bb[i+0] = f2bf(bv.x); bb[i+1] = f2bf(bv.y); bb[i+2] = f2bf(bv.z); bb[i+3] = f2bf(bv.w);
            }
            *(uint4*)&As[srow][sk]     = *(uint4*)&ab[0];
            *(uint4*)&As[srow][sk + 8] = *(uint4*)&ab[8];
            *(uint4*)&Bs[srow][sk]     = *(uint4*)&bb[0];
            *(uint4*)&Bs[srow][sk + 8] = *(uint4*)&bb[8];
        }
        __syncthreads();

        #pragma unroll
        for (int ks = 0; ks < 2; ++ks) {
            s16x8 af[2], bfr[2];
            #pragma unroll
            for (int mf = 0; mf < 2; ++mf) {
                uint4 v = *(uint4*)&As[wm*64 + mf*32 + l31][ks*16 + lh*8];
                af[mf] = *(s16x8*)&v;
            }
            #pragma unroll
            for (int nf = 0; nf < 2; ++nf) {
                uint4 v = *(uint4*)&Bs[wn*64 + nf*32 + l31][ks*16 + lh*8];
                bfr[nf] = *(s16x8*)&v;
            }
            #pragma unroll
            for (int mf = 0; mf < 2; ++mf)
                #pragma unroll
                for (int nf = 0; nf < 2; ++nf)
                    acc[mf][nf] = __builtin_amdgcn_mfma_f32_32x32x16_bf16(
                        af[mf], bfr[nf], acc[mf][nf], 0, 0, 0);
        }
    }

    // store C: C/D layout col=lane&31, row=(reg&3)+8*(reg>>2)+4*(lane>>5)
    const float osc = (z == 0) ? 0.044194173824159216f : 1.0f;  // fold 1/sqrt(512) into Q
    u16* __restrict__ O = (z == 0) ? Qo : Ko;
    #pragma unroll
    for (int mf = 0; mf < 2; ++mf)
        #pragma unroll
        for (int nf = 0; nf < 2; ++nf)
            #pragma unroll
            for (int r = 0; r < 16; ++r) {
                const int mi = a0 + wm*64 + mf*32 + (r & 3) + 8*(r >> 2) + 4*lh;
                const int ni = b0 + wn*64 + nf*32 + l31;
                const u16 v = f2bf(acc[mf][nf][r] * osc);
                if (z < 2) {
                    O[(size_t)mi * PD + ni] = v;
                } else {
                    const int bb_ = ni >> 11, ll = ni & 2047;       // token -> (b, l)
                    Vt[((size_t)(bb_ * 512 + mi)) * 2048 + ll] = v; // mi = h*64+dh
                }
            }
}

// ======================= Flash attention (MFMA) =======================
// Block = (b, h, 128-q tile); 4 waves x 32 q. 64-key tiles.
// S^T = K·Q^T  (C col = q = lane&31 -> softmax state per-lane scalar)
// O^T = V^T·P^T (A = Vts contiguous-key rows, B = P2[q][key] contiguous-key)
__global__ __launch_bounds__(256) void attn_mfma(
    const u16* __restrict__ Qp, const u16* __restrict__ Kp, const u16* __restrict__ Vt,
    const float* __restrict__ query, float* __restrict__ out)
{
    const int qt = blockIdx.x;   // 0..15
    const int h  = blockIdx.y;   // 0..7
    const int b  = blockIdx.z;   // 0..3
    const int q0 = qt * 128;
    const int L = 2048;

    __shared__ uint4 lds_u4[36864 / 16];
    u16* Ks   = (u16*)lds_u4;            // [64][72] keys x dh
    u16* Vts  = Ks + 64 * 72;            // [64][72] dh x keys
    u16* P2a  = Vts + 64 * 72;           // [4][32][72] per-wave P (q x key)
    float* Oe = (float*)lds_u4;          // [128][68] epilogue overlay

    const int tid  = threadIdx.x;
    const int wave = tid >> 6, lane = tid & 63;
    const int l31 = lane & 31, lh = lane >> 5;
    u16* P2 = P2a + wave * 32 * 72;

    // Q fragments in registers: B-frag n = q = lane&31, k = dh contiguous
    const int qrow = b * L + q0 + wave * 32 + l31;
    s16x8 qf[4];
    #pragma unroll
    for (int ds = 0; ds < 4; ++ds) {
        uint4 v = *(const uint4*)(Qp + (size_t)qrow * PD + h*64 + ds*16 + lh*8);
        qf[ds] = *(s16x8*)&v;
    }

    f32x16 ot[2];
    #pragma unroll
    for (int mf = 0; mf < 2; ++mf)
        #pragma unroll
        for (int r = 0; r < 16; ++r) ot[mf][r] = 0.f;
    float m_i = -INFINITY, l_i = 0.f;

    const int srow = tid >> 2;          // 0..63
    const int sc   = (tid & 3) * 16;    // 0,16,32,48

    for (int k0 = 0; k0 < L; k0 += 64) {
        __syncthreads();
        {
            const u16* kp = Kp + (size_t)(b*L + k0 + srow) * PD + h*64 + sc;
            const u16* vp = Vt + ((size_t)((b*8 + h)*64 + srow)) * 2048 + k0 + sc;
            uint4 k0v = *(const uint4*)kp;
            uint4 k1v = *(const uint4*)(kp + 8);
            uint4 v0v = *(const uint4*)vp;
            uint4 v1v = *(const uint4*)(vp + 8);
            *(uint4*)&Ks [srow*72 + sc]     = k0v;
            *(uint4*)&Ks [srow*72 + sc + 8] = k1v;
            *(uint4*)&Vts[srow*72 + sc]     = v0v;
            *(uint4*)&Vts[srow*72 + sc + 8] = v1v;
        }
        __syncthreads();

        // S^T = K·Q^T : rows=key, cols=q
        f32x16 s[2];
        #pragma unroll
        for (int kf = 0; kf < 2; ++kf) {
            #pragma unroll
            for (int r = 0; r < 16; ++r) s[kf][r] = 0.f;
            #pragma unroll
            for (int ds = 0; ds < 4; ++ds) {
                uint4 av = *(uint4*)&Ks[(kf*32 + l31)*72 + ds*16 + lh*8];
                s[kf] = __builtin_amdgcn_mfma_f32_32x32x16_bf16(
                    *(s16x8*)&av, qf[ds], s[kf], 0, 0, 0);
            }
        }

        // online softmax (q = lane&31; scores pre-scaled via Q)
        float rm = -INFINITY;
        #pragma unroll
        for (int kf = 0; kf < 2; ++kf)
            #pragma unroll
            for (int r = 0; r < 16; ++r) rm = fmaxf(rm, s[kf][r]);
        rm = fmaxf(rm, __shfl_xor(rm, 32));
        const float m_new = fmaxf(m_i, rm);
        const float alpha = __expf(m_i - m_new);
        float rs = 0.f;
        u16 pb[2][16];
        #pragma unroll
        for (int kf = 0; kf < 2; ++kf)
            #pragma unroll
            for (int r = 0; r < 16; ++r) {
                const float p = __expf(s[kf][r] - m_new);
                rs += p;
                pb[kf][r] = f2bf(p);
            }
        rs += __shfl_xor(rs, 32);
        l_i = l_i * alpha + rs;
        m_i = m_new;
        #pragma unroll
        for (int mf = 0; mf < 2; ++mf)
            #pragma unroll
            for (int r = 0; r < 16; ++r) ot[mf][r] *= alpha;

        // P -> LDS: P2[q][key], key=(reg&3)+8*(reg>>2)+4*lh+32*kf contiguous per reg-quad
        #pragma unroll
        for (int kf = 0; kf < 2; ++kf)
            #pragma unroll
            for (int g = 0; g < 4; ++g) {
                const u32 lo = (u32)pb[kf][g*4+0] | ((u32)pb[kf][g*4+1] << 16);
                const u32 hi = (u32)pb[kf][g*4+2] | ((u32)pb[kf][g*4+3] << 16);
                uint2 w2; w2.x = lo; w2.y = hi;
                *(uint2*)&P2[l31*72 + kf*32 + g*8 + lh*4] = w2;
            }
        // (wave-private P2: in-wave lgkmcnt ordering suffices, no barrier)

        // O^T += V^T · P^T : A = Vts rows (dh), B = P2 rows (q), contract key
        #pragma unroll
        for (int ks = 0; ks < 4; ++ks) {
            uint4 bv = *(uint4*)&P2[l31*72 + ks*16 + lh*8];
            s16x8 bfr = *(s16x8*)&bv;
            #pragma unroll
            for (int mf = 0; mf < 2; ++mf) {
                uint4 av = *(uint4*)&Vts[(mf*32 + l31)*72 + ks*16 + lh*8];
                ot[mf] = __builtin_amdgcn_mfma_f32_32x32x16_bf16(
                    *(s16x8*)&av, bfr, ot[mf], 0, 0, 0);
            }
        }
    }

    // epilogue: O^T (col=q, row=dh) -> LDS transpose -> coalesced fp32 + residual
    __syncthreads();   // all waves done with Ks/Vts/P2 before overlay
    const float inv_l = 1.0f / l_i;
    #pragma unroll
    for (int mf = 0; mf < 2; ++mf)
        #pragma unroll
        for (int g = 0; g < 4; ++g) {
            float4 v;
            v.x = ot[mf][g*4+0] * inv_l;
            v.y = ot[mf][g*4+1] * inv_l;
            v.z = ot[mf][g*4+2] * inv_l;
            v.w = ot[mf][g*4+3] * inv_l;
            const int dh0 = mf*32 + 8*g + 4*lh;
            *(float4*)&Oe[(wave*32 + l31)*68 + dh0] = v;
        }
    __syncthreads();
    {
        const int r  = tid >> 1;           // 0..127
        const int c0 = (tid & 1) * 32;
        const size_t gb = ((size_t)(b*L + q0 + r)) * PD + h*64 + c0;
        #pragma unroll
        for (int i = 0; i < 8; ++i) {
            float4 ov = *(float4*)&Oe[r*68 + c0 + 4*i];
            float4 qv = *(const float4*)(query + gb + 4*i);
            ov.x += qv.x; ov.y += qv.y; ov.z += qv.z; ov.w += qv.w;
            *(float4*)(out + gb + 4*i) = ov;
        }
    }
}

// ======================= launch =======================
extern "C" void kernel_launch(void* const* d_in, const int* in_sizes, int n_in,
                              void* d_out, int out_size, void* d_ws, size_t ws_size,
                              hipStream_t stream) {
    const float* query = (const float*)d_in[0];   // [4,2048,512] fp32
    const float* keys  = (const float*)d_in[1];   // [4,2048,512] fp32
    const float* Wq    = (const float*)d_in[2];   // [512,512] fp32
    const float* Wk    = (const float*)d_in[3];
    const float* Wv    = (const float*)d_in[4];
    float* out = (float*)d_out;

    // workspace: Qp,Kp [8192][512] bf16 + Vt [2048][2048] bf16 = 24 MB
    u16* Qp = (u16*)d_ws;
    u16* Kp = Qp + (size_t)8192 * 512;
    u16* Vt = Kp + (size_t)8192 * 512;

    proj_mfma<<<dim3(64, 4, 3), 256, 0, stream>>>(query, keys, Wq, Wk, Wv, Qp, Kp, Vt);
    attn_mfma<<<dim3(16, 8, 4), 256, 0, stream>>>(Qp, Kp, Vt, query, out);
}